// Round 3
// baseline (321.712 us; speedup 1.0000x reference)
//
#include <hip/hip_runtime.h>
#include <math.h>

#define D4    512           // 2048 dims / 4 per float4
#define NTOK  16384         // B*T
#define NW6   (NTOK * 6)    // weights (and indices) chunk size

// One 16-lane group per token (4 tokens/wave, 16/block). Lane l16 covers
// float4 elements {c*16+l16} of the token's row; 18 scalar accumulators per
// lane (static indexing only -> registers). W addresses are identical across
// the wave's 4 groups -> one broadcast 256B fetch per load instruction.
// Grid = 1024 blocks -> 16 waves/CU for latency hiding.
__global__ __launch_bounds__(256, 4) void router_kernel(
    const float* __restrict__ x,
    const float* __restrict__ We,
    const float* __restrict__ Wg,
    float* __restrict__ out,
    unsigned int* __restrict__ gcounts)
{
    __shared__ unsigned int lcnt[16];
    const int tid = threadIdx.x;
    if (tid < 16) lcnt[tid] = 0u;
    __syncthreads();

    const int wave = tid >> 6;
    const int lane = tid & 63;
    const int grp  = lane >> 4;   // 0..3 : which token of the wave
    const int l16  = lane & 15;

    const int tok = (blockIdx.x * 4 + wave) * 4 + grp;

    const float4* __restrict__ x4  = reinterpret_cast<const float4*>(x);
    const float4* __restrict__ We4 = reinterpret_cast<const float4*>(We);
    const float4* __restrict__ Wg4 = reinterpret_cast<const float4*>(Wg);
    const float4* __restrict__ xp  = x4 + (size_t)tok * D4;

    float acc[18];
#pragma unroll
    for (int e = 0; e < 18; ++e) acc[e] = 0.f;

#pragma unroll 2
    for (int c = 0; c < 32; ++c) {
        const int off = c * 16 + l16;
        const float4 xv = xp[off];              // issue longest-latency first
#pragma unroll
        for (int e = 0; e < 16; ++e) {
            const float4 wv = We4[e * D4 + off];
            acc[e] += wv.x * xv.x + wv.y * xv.y + wv.z * xv.z + wv.w * xv.w;
        }
#pragma unroll
        for (int g = 0; g < 2; ++g) {
            const float4 wv = Wg4[g * D4 + off];
            acc[16 + g] += wv.x * xv.x + wv.y * xv.y + wv.z * xv.z + wv.w * xv.w;
        }
    }

    // 4-step butterfly within the 16-lane group (xor masks stay in-group).
#pragma unroll
    for (int e = 0; e < 18; ++e) {
        float v = acc[e];
        v += __shfl_xor(v, 8, 64);
        v += __shfl_xor(v, 4, 64);
        v += __shfl_xor(v, 2, 64);
        v += __shfl_xor(v, 1, 64);
        acc[e] = v;
    }

    // Lane 0 of each group routes its token. All array indices static.
    if (l16 == 0) {
        const float g0 = 1.f / (1.f + expf(-acc[16]));
        const float g1 = 1.f / (1.f + expf(-acc[17]));

        // --- Group A: experts 0..7, top-1 of softmax ---
        int aidx = 0; float amax = acc[0];
#pragma unroll
        for (int i = 1; i < 8; ++i)
            if (acc[i] > amax) { amax = acc[i]; aidx = i; }
        float asum = 0.f;
#pragma unroll
        for (int i = 0; i < 8; ++i) asum += expf(acc[i] - amax);
        const float a_best = 1.f / asum;

        // --- Group B: experts 8..11, top-1, gated by g0 ---
        int bidx = 0; float bmax = acc[8];
#pragma unroll
        for (int i = 1; i < 4; ++i)
            if (acc[8 + i] > bmax) { bmax = acc[8 + i]; bidx = i; }
        float bsum = 0.f;
#pragma unroll
        for (int i = 0; i < 4; ++i) bsum += expf(acc[8 + i] - bmax);
        const float b_w = (g0 > 0.15f) ? ((1.f / bsum) * g0) : 0.f;

        // --- Group C: experts 12..15, top-2 of softmax, gated by g1 ---
        int c1 = 0; float cmax = acc[12];
#pragma unroll
        for (int i = 1; i < 4; ++i)
            if (acc[12 + i] > cmax) { cmax = acc[12 + i]; c1 = i; }
        float csum = 0.f;
#pragma unroll
        for (int i = 0; i < 4; ++i) csum += expf(acc[12 + i] - cmax);
        int c2 = -1; float c2v = -1e30f;
#pragma unroll
        for (int i = 0; i < 4; ++i)
            if (i != c1 && acc[12 + i] > c2v) { c2v = acc[12 + i]; c2 = i; }
        const float cg   = (g1 > 0.15f) ? g1 : 0.f;
        const float c_w1 = (1.f / csum) * cg;
        const float c_w2 = (expf(c2v - cmax) / csum) * cg;

        // --- normalize and write (float2 stores, 8B-aligned) ---
        const float inv = 1.f / (a_best + b_w + c_w1 + c_w2 + 1e-8f);
        float2* ow = reinterpret_cast<float2*>(out + (size_t)tok * 6);
        ow[0] = make_float2(a_best * inv, b_w * inv);
        ow[1] = make_float2(c_w1 * inv, c_w2 * inv);
        ow[2] = make_float2(0.f, 0.f);
        float2* oi = reinterpret_cast<float2*>(out + NW6 + (size_t)tok * 6);
        oi[0] = make_float2((float)aidx, (float)(8 + bidx));
        oi[1] = make_float2((float)(12 + c1), (float)(12 + c2));
        oi[2] = make_float2(0.f, 0.f);

        atomicAdd(&lcnt[aidx], 1u);
        atomicAdd(&lcnt[8 + bidx], 1u);
        atomicAdd(&lcnt[12 + c1], 1u);
        atomicAdd(&lcnt[12 + c2], 1u);
    }

    __syncthreads();
    if (tid < 16) {
        const unsigned int c = lcnt[tid];
        if (c) atomicAdd(&gcounts[tid], c);
    }
    __syncthreads();   // all 16 count-atomics issued+drained before the ticket

    // Last-block ticket computes the aux loss (replaces a second kernel).
    // Reference bincount includes 2 zero-pad indices/token -> expert 0 gets
    // +2*NTOK analytically; total = 6*NTOK.
    if (tid == 0) {
        __threadfence();
        const unsigned int t = atomicAdd(&gcounts[16], 1u);
        if (t == gridDim.x - 1) {
            const float total = 6.0f * (float)NTOK;
            const float uni = 1.0f / 16.0f;
            float aux = 0.f;
            for (int e = 0; e < 16; ++e) {
                float c = (float)atomicAdd(&gcounts[e], 0u)  // coherent read
                          + (e == 0 ? 2.0f * (float)NTOK : 0.0f);
                aux += uni * (logf(uni) - logf(c / total));
            }
            out[2 * NW6] = aux * 0.01f;
        }
    }
}

extern "C" void kernel_launch(void* const* d_in, const int* in_sizes, int n_in,
                              void* d_out, int out_size, void* d_ws, size_t ws_size,
                              hipStream_t stream)
{
    const float* x  = (const float*)d_in[0];   // (4,4096,2048)
    const float* We = (const float*)d_in[1];   // (16,2048)
    const float* Wg = (const float*)d_in[2];   // (2,2048)
    float* out = (float*)d_out;
    unsigned int* counts = (unsigned int*)d_ws;

    hipMemsetAsync(counts, 0, 17 * sizeof(unsigned int), stream);

    const int blocks = NTOK / 16;              // 4 tok/wave * 4 waves = 16
    router_kernel<<<blocks, 256, 0, stream>>>(x, We, Wg, out, counts);
}